// Round 4
// baseline (379.360 us; speedup 1.0000x reference)
//
#include <hip/hip_runtime.h>

typedef int v4i __attribute__((ext_vector_type(4)));
typedef int v16i __attribute__((ext_vector_type(16)));

#define IN_F   3072
#define PAD    4096
#define M_ROWS 8192
#define N_OUT  4096

#define BM 256
#define BN 256
#define BK 64
#define TBUF (BM * BK)    // 16 KB per A/B tile buffer
#define TTILES (PAD / BK) // 64 K-tiles

// ---------------------------------------------------------------------------
// async 16B global -> LDS copy. Integer round-trip casts: guaranteed to
// compile; LDS aperture on gfx9 is 4GB-aligned so low-32 truncation of the
// flat address IS the LDS offset. HW dest = wave-uniform base + lane*16.
// ---------------------------------------------------------------------------
__device__ __forceinline__ void async_copy16(const void* g, void* l) {
    __builtin_amdgcn_global_load_lds(
        (__attribute__((address_space(1))) const void*)(uintptr_t)g,
        (__attribute__((address_space(3))) void*)(uint32_t)(uintptr_t)l,
        16, 0, 0);
}

// unnormalized FWHT over 16 register values
__device__ __forceinline__ void fwht16(float v[16]) {
#pragma unroll
    for (int s = 1; s < 16; s <<= 1) {
#pragma unroll
        for (int i = 0; i < 16; i++) {
            if ((i & s) == 0) {
                float a = v[i], b = v[i ^ s];
                v[i]     = a + b;
                v[i ^ s] = a - b;
            }
        }
    }
}

// ---------------------------------------------------------------------------
// One row per block: load 3072 floats (zero-pad to 4096), FWHT-4096 as
// FWHT16 (x) FWHT16 (x) FWHT16 with two XOR-swizzled LDS exchanges
// (<=2-way bank aliasing on every access = free), then 8-bit affine
// quantize; store (q-128) as int8 and the row sum of (q-128).
// index decomposition: k = 256*k2 + 16*k1 + k0
// ---------------------------------------------------------------------------
__global__ __launch_bounds__(256) void fwht_quant_kernel(
    const float* __restrict__ in, signed char* __restrict__ qout,
    int* __restrict__ rowsum, int nrows)
{
    __shared__ float lds[4096];
    __shared__ int ssum;
    const int t = threadIdx.x;
    const int r = blockIdx.x;
    if (r >= nrows) return;
    const float* row = in + (size_t)r * IN_F;

    // load: reg j (=k2) holds element 256*j + t  (perfectly coalesced; 3072 = 12*256)
    float v[16];
#pragma unroll
    for (int j = 0; j < 16; j++)
        v[j] = (j < 12) ? row[j * 256 + t] : 0.0f;

    fwht16(v);                      // over k2

    const int th = t >> 4, tl = t & 15;   // (k1,k0) for now

    // exchange 1: layout phys(k2,k1,k0) = 256*k2 + 16*(k1^k2) + (k0^k1)
    #pragma unroll
    for (int j = 0; j < 16; j++)
        lds[256 * j + 16 * (th ^ j) + (tl ^ th)] = v[j];   // (k2=j,k1=th,k0=tl)
    __syncthreads();
#pragma unroll
    for (int j = 0; j < 16; j++)                            // now (k2=th,k0=tl), regs k1
        v[j] = lds[256 * th + 16 * (j ^ th) + (tl ^ j)];

    fwht16(v);                      // over k1

    if (t == 0) ssum = 0;
    __syncthreads();                // protects lds reuse + ssum init

    // exchange 2: layout phys(k2,k1,k0) = 256*k2 + 16*(k1^k2) + (k0^k1)
#pragma unroll
    for (int j = 0; j < 16; j++)                            // (k2=th,k1=j,k0=tl)
        lds[256 * th + 16 * (j ^ th) + (tl ^ j)] = v[j];
    __syncthreads();
#pragma unroll
    for (int j = 0; j < 16; j++)                            // now (k2=th,k1=tl), regs k0
        v[j] = lds[256 * th + 16 * (tl ^ th) + (j ^ tl)];

    fwht16(v);                      // over k0 -> thread t holds elements [16t,16t+16)

    // quantize: q = clip(round((clip(x,+-384)+384)/s),0,255); store a=q-128
    // 1/s = 255/768 = 85/256 exactly representable in f32
    const float INV = 0.33203125f;
    int sum = 0;
    int pk[4];
#pragma unroll
    for (int c = 0; c < 4; c++) {
        int word = 0;
#pragma unroll
        for (int b = 0; b < 4; b++) {
            float x = v[c * 4 + b];
            x = fminf(fmaxf(x, -384.0f), 384.0f);
            float qf = rintf((x + 384.0f) * INV);
            int qi = (int)qf;
            qi = qi < 0 ? 0 : (qi > 255 ? 255 : qi);
            int a = qi - 128;
            sum += a;
            word |= (a & 255) << (8 * b);
        }
        pk[c] = word;
    }

    // row-sum: wave shuffle reduce, then one LDS atomic per wave
#pragma unroll
    for (int off = 32; off > 0; off >>= 1) sum += __shfl_down(sum, off, 64);
    if ((t & 63) == 0) atomicAdd(&ssum, sum);

    ((int4*)(qout + (size_t)r * PAD))[t] = make_int4(pk[0], pk[1], pk[2], pk[3]);

    __syncthreads();
    if (t == 0) rowsum[r] = ssum;
}

// ---------------------------------------------------------------------------
// int8 GEMM v4: m201-style phase sandwich.
// C[m,n] = sum_k A[m,k]*B[n,k] (both K-major), then affine fixup.
//
// Tile 256x256, BK=64. 8 waves in 2M x 4N grid; per-wave output 128x64 =
// acc[4][2] of mfma 32x32x32 i8. LDS: triple-buffered 16KB A + 16KB B =
// 96 KB -> 1 block/CU, 2 waves/SIMD.
//
// Phase = one K=32 slice (ks): { 6 ds_read_b128 (4 A-frag + 2 B-frag);
// issue 2 global_load_lds for tile t+2; BARRIER; lgkmcnt(0)+sched_barrier;
// setprio(1); 8 MFMA; setprio(0); [phase 1: vmcnt wait]; BARRIER }.
// The pre-MFMA barrier + fat 8-MFMA cluster breaks the v3 convoy (all
// waves bursting LDS then bursting MFMA in lockstep): ds_read latency
// drains during the barrier, and setprio staggers the 2 waves/SIMD so
// one wave's MFMA cluster covers the other's read/stage window.
//
// vmcnt ledger: 4 gloads/wave/tile, issued 2/phase. At phase-1 wait:
// outstanding = {t+1}'s 4 + {t+2}'s 4 -> vmcnt(4) retires t+1 exactly.
// Tail: t=TTILES-2 has only {t+1}'s 4 outstanding -> vmcnt(0). Never
// drains in steady state. Buffer-reuse safe: stage into ob2 happens 2+
// barriers after the last reads of that physical buffer completed.
//
// LDS chunk-rotation swizzle (verified): physical 16B chunk p of row r
// holds logical chunk q = (p - (r>>1)) & 3; fragment slot in the 128B
// window is (r&1)*64 + p*16 -> 8 consecutive lanes cover all 8 slots.
//
// epilogue: out = D*kA + (SA[m]+SB[n])*kS + kC + bias[n]
// ---------------------------------------------------------------------------
__global__ __launch_bounds__(512, 2) void gemm_i8_kernel(
    const signed char* __restrict__ A, const signed char* __restrict__ B,
    const int* __restrict__ SA, const int* __restrict__ SB,
    const float* __restrict__ bias, float* __restrict__ out,
    float kA, float kS, float kC)
{
    __shared__ __align__(16) signed char As[3 * TBUF];
    __shared__ __align__(16) signed char Bs[3 * TBUF];

    const int tid  = threadIdx.x;
    const int lane = tid & 63;
    const int wid  = tid >> 6;          // 0..7
    const int wr   = wid >> 2;          // 0..1 (M)
    const int wc   = wid & 3;           // 0..3 (N)
    const int l5   = lane >> 5;
    const int lm   = lane & 31;

    // XCD-aware swizzle: grid=512, nwg%8==0. XCD k (= bid%8) gets 64
    // consecutive logical ids = 4 consecutive 256-row A panels.
    const int bid = (int)blockIdx.x;
    const int swz = ((bid & 7) << 6) | (bid >> 3);
    const int bm  = (swz >> 4) * BM;
    const int bn  = (swz & 15) * BN;

    v16i acc[4][2];
#pragma unroll
    for (int i = 0; i < 4; i++)
#pragma unroll
        for (int j = 0; j < 2; j++)
#pragma unroll
            for (int e = 0; e < 16; e++)
                acc[i][j][e] = 0;

    // ---- staging addressing (per-lane constants) ----
    const signed char* srcA[2];
    const signed char* srcB[2];
    int dstO[2];
#pragma unroll
    for (int i = 0; i < 2; i++) {
        int c  = wid * 128 + i * 64 + lane;
        int rr = c >> 2, p = c & 3;
        int q  = (p - (rr >> 1)) & 3;          // logical chunk stored at p
        srcA[i] = A + (size_t)(bm + rr) * PAD + q * 16;
        srcB[i] = B + (size_t)(bn + rr) * PAD + q * 16;
        dstO[i] = (wid * 128 + i * 64) * 16;   // wave-uniform LDS base
    }

    // ---- fragment read offsets (per-lane constants) ----
    int aoff[4][2], boff[2][2];
#pragma unroll
    for (int mt = 0; mt < 4; mt++) {
        int rr = wr * 128 + mt * 32 + lm;
#pragma unroll
        for (int ks = 0; ks < 2; ks++) {
            int p = (ks * 2 + l5 + (rr >> 1)) & 3;
            aoff[mt][ks] = rr * 64 + p * 16;
        }
    }
#pragma unroll
    for (int nt = 0; nt < 2; nt++) {
        int rr = wc * 64 + nt * 32 + lm;
#pragma unroll
        for (int ks = 0; ks < 2; ks++) {
            int p = (ks * 2 + l5 + (rr >> 1)) & 3;
            boff[nt][ks] = rr * 64 + p * 16;
        }
    }

    // ---- prologue: stage tiles 0 and 1; wait tile 0 (tile 1 in flight) ----
#pragma unroll
    for (int i = 0; i < 2; i++) async_copy16(srcA[i],      As + dstO[i]);
#pragma unroll
    for (int i = 0; i < 2; i++) async_copy16(srcB[i],      Bs + dstO[i]);
#pragma unroll
    for (int i = 0; i < 2; i++) async_copy16(srcA[i] + BK, As + TBUF + dstO[i]);
#pragma unroll
    for (int i = 0; i < 2; i++) async_copy16(srcB[i] + BK, Bs + TBUF + dstO[i]);
    asm volatile("s_waitcnt vmcnt(4)" ::: "memory");
    __builtin_amdgcn_s_barrier();
    asm volatile("" ::: "memory");

    int ob0 = 0, ob1 = TBUF, ob2 = 2 * TBUF;

    for (int t = 0; t < TTILES; ++t) {
        const signed char* Ab = As + ob0;
        const signed char* Bb = Bs + ob0;
        const int  pk = (t + 2) * BK;
        const bool pf = (t + 2 < TTILES);

        // ================= phase 0 : ks = 0 =================
        {
            v4i a0 = *(const v4i*)(Ab + aoff[0][0]);
            v4i a1 = *(const v4i*)(Ab + aoff[1][0]);
            v4i a2 = *(const v4i*)(Ab + aoff[2][0]);
            v4i a3 = *(const v4i*)(Ab + aoff[3][0]);
            v4i b0 = *(const v4i*)(Bb + boff[0][0]);
            v4i b1 = *(const v4i*)(Bb + boff[1][0]);
            if (pf) {
                async_copy16(srcA[0] + pk, As + ob2 + dstO[0]);
                async_copy16(srcA[1] + pk, As + ob2 + dstO[1]);
            }
            // pre-MFMA barrier: reads issued above drain while waves sync
            asm volatile("" ::: "memory");
            __builtin_amdgcn_s_barrier();
            asm volatile("s_waitcnt lgkmcnt(0)" ::: "memory");
            __builtin_amdgcn_sched_barrier(0);
            __builtin_amdgcn_s_setprio(1);
            acc[0][0] = __builtin_amdgcn_mfma_i32_32x32x32_i8(a0, b0, acc[0][0], 0, 0, 0);
            acc[0][1] = __builtin_amdgcn_mfma_i32_32x32x32_i8(a0, b1, acc[0][1], 0, 0, 0);
            acc[1][0] = __builtin_amdgcn_mfma_i32_32x32x32_i8(a1, b0, acc[1][0], 0, 0, 0);
            acc[1][1] = __builtin_amdgcn_mfma_i32_32x32x32_i8(a1, b1, acc[1][1], 0, 0, 0);
            acc[2][0] = __builtin_amdgcn_mfma_i32_32x32x32_i8(a2, b0, acc[2][0], 0, 0, 0);
            acc[2][1] = __builtin_amdgcn_mfma_i32_32x32x32_i8(a2, b1, acc[2][1], 0, 0, 0);
            acc[3][0] = __builtin_amdgcn_mfma_i32_32x32x32_i8(a3, b0, acc[3][0], 0, 0, 0);
            acc[3][1] = __builtin_amdgcn_mfma_i32_32x32x32_i8(a3, b1, acc[3][1], 0, 0, 0);
            __builtin_amdgcn_s_setprio(0);
            asm volatile("" ::: "memory");
            __builtin_amdgcn_s_barrier();
            asm volatile("" ::: "memory");
        }

        // ================= phase 1 : ks = 1 =================
        {
            v4i a0 = *(const v4i*)(Ab + aoff[0][1]);
            v4i a1 = *(const v4i*)(Ab + aoff[1][1]);
            v4i a2 = *(const v4i*)(Ab + aoff[2][1]);
            v4i a3 = *(const v4i*)(Ab + aoff[3][1]);
            v4i b0 = *(const v4i*)(Bb + boff[0][1]);
            v4i b1 = *(const v4i*)(Bb + boff[1][1]);
            if (pf) {
                async_copy16(srcB[0] + pk, Bs + ob2 + dstO[0]);
                async_copy16(srcB[1] + pk, Bs + ob2 + dstO[1]);
            }
            asm volatile("" ::: "memory");
            __builtin_amdgcn_s_barrier();
            asm volatile("s_waitcnt lgkmcnt(0)" ::: "memory");
            __builtin_amdgcn_sched_barrier(0);
            __builtin_amdgcn_s_setprio(1);
            acc[0][0] = __builtin_amdgcn_mfma_i32_32x32x32_i8(a0, b0, acc[0][0], 0, 0, 0);
            acc[0][1] = __builtin_amdgcn_mfma_i32_32x32x32_i8(a0, b1, acc[0][1], 0, 0, 0);
            acc[1][0] = __builtin_amdgcn_mfma_i32_32x32x32_i8(a1, b0, acc[1][0], 0, 0, 0);
            acc[1][1] = __builtin_amdgcn_mfma_i32_32x32x32_i8(a1, b1, acc[1][1], 0, 0, 0);
            acc[2][0] = __builtin_amdgcn_mfma_i32_32x32x32_i8(a2, b0, acc[2][0], 0, 0, 0);
            acc[2][1] = __builtin_amdgcn_mfma_i32_32x32x32_i8(a2, b1, acc[2][1], 0, 0, 0);
            acc[3][0] = __builtin_amdgcn_mfma_i32_32x32x32_i8(a3, b0, acc[3][0], 0, 0, 0);
            acc[3][1] = __builtin_amdgcn_mfma_i32_32x32x32_i8(a3, b1, acc[3][1], 0, 0, 0);
            __builtin_amdgcn_s_setprio(0);
            // tile-boundary wait: retire tile t+1's staging (oldest 4)
            if (t < TTILES - 1) {
                if (pf) asm volatile("s_waitcnt vmcnt(4)" ::: "memory");
                else    asm volatile("s_waitcnt vmcnt(0)" ::: "memory");
                __builtin_amdgcn_s_barrier();
                asm volatile("" ::: "memory");
            }
        }

        int tmp = ob0; ob0 = ob1; ob1 = ob2; ob2 = tmp;
    }

    // ---- epilogue: C/D layout col=lane&31, row=(e&3)+8*(e>>2)+4*(lane>>5) ----
#pragma unroll
    for (int nt = 0; nt < 2; nt++) {
        int n = bn + wc * 64 + nt * 32 + lm;
        float ct = (float)SB[n] * kS + kC + bias[n];
#pragma unroll
        for (int mt = 0; mt < 4; mt++) {
#pragma unroll
            for (int e = 0; e < 16; e++) {
                int m = bm + wr * 128 + mt * 32 + l5 * 4 + (e & 3) + 8 * (e >> 2);
                out[(size_t)m * N_OUT + n] =
                    (float)acc[mt][nt][e] * kA + (float)SA[m] * kS + ct;
            }
        }
    }
}

// ---------------------------------------------------------------------------
extern "C" void kernel_launch(void* const* d_in, const int* in_sizes, int n_in,
                              void* d_out, int out_size, void* d_ws, size_t ws_size,
                              hipStream_t stream) {
    const float* x    = (const float*)d_in[0];   // [2,4096,3072]
    const float* w    = (const float*)d_in[1];   // [4096,3072]
    const float* bias = (const float*)d_in[2];   // [4096]
    float* out = (float*)d_out;                  // [2,4096,4096]

    // workspace: qa 32MB | qb 16MB | SA 32KB | SB 16KB  (~48MB total)
    signed char* qa = (signed char*)d_ws;
    signed char* qb = qa + (size_t)M_ROWS * PAD;
    int* SA = (int*)(qb + (size_t)N_OUT * PAD);
    int* SB = SA + M_ROWS;

    fwht_quant_kernel<<<M_ROWS, 256, 0, stream>>>(x, qa, SA, M_ROWS);
    fwht_quant_kernel<<<N_OUT,  256, 0, stream>>>(w, qb, SB, N_OUT);

    // out = (s^2*D + s*c*(SA+SB) + K*c^2)/K + bias,  s=768/255, c=128s-384=384/255
    double s = 768.0 / 255.0;
    double c = 384.0 / 255.0;
    float kA = (float)(s * s / PAD);
    float kS = (float)(s * c / PAD);
    float kC = (float)(c * c);

    dim3 grid((M_ROWS / BM) * (N_OUT / BN));     // 512 blocks, 1D for swizzle
    gemm_i8_kernel<<<grid, 512, 0, stream>>>(qa, qb, SA, SB, bias, out, kA, kS, kC);
}